// Round 1
// baseline (1049.039 us; speedup 1.0000x reference)
//
#include <hip/hip_runtime.h>
#include <float.h>

#define BATCH 8
#define SEQ   1024
#define CDIM  512
#define HEADS 8
#define HD    64
#define TOPK  16
#define MTOT  (BATCH*SEQ)   // 8192

// ---------------- GEMM tile config ----------------
#define BM 128
#define BN 128
#define BKK 32

// ============================================================
// Kernel 1: fused QKV projection.
//   Y = x @ [Wq | Wkv] + [bq | bkv];  relu on q part.
//   Scatter to q_ws/k_ws/v_ws in [B,H,N,D] layout.
// ============================================================
__global__ __launch_bounds__(256) void qkv_gemm_kernel(
    const float* __restrict__ x,
    const float* __restrict__ Wq,  const float* __restrict__ bq,
    const float* __restrict__ Wkv, const float* __restrict__ bkv,
    float* __restrict__ q_ws, float* __restrict__ k_ws, float* __restrict__ v_ws)
{
    __shared__ float a_s[BKK][BM + 4];   // k-major (transposed) A tile, +4 pad
    __shared__ float b_s[BKK][BN];

    const int bm = blockIdx.x;           // 0..63
    const int bn = blockIdx.y;           // 0..11 (0..3 = q, 4..7 = k, 8..11 = v)
    const int tid = threadIdx.x;
    const int tx = tid & 15, ty = tid >> 4;
    const int row0 = bm * BM;

    const float* Bp; int ldb, bc0;
    if (bn < 4) { Bp = Wq;  ldb = CDIM;     bc0 = bn * BN; }
    else        { Bp = Wkv; ldb = 2 * CDIM; bc0 = bn * BN - CDIM; }

    float acc[8][8];
    #pragma unroll
    for (int i = 0; i < 8; i++)
        #pragma unroll
        for (int j = 0; j < 8; j++) acc[i][j] = 0.f;

    for (int kt = 0; kt < CDIM; kt += BKK) {
        // A tile: 128 rows x 32 k, float4 loads along k, transposed store
        #pragma unroll
        for (int i = 0; i < 4; i++) {
            int f = tid + i * 256;
            int r  = f >> 3;
            int kq = f & 7;
            float4 av = *(const float4*)(x + (size_t)(row0 + r) * CDIM + kt + kq * 4);
            a_s[kq*4+0][r] = av.x;
            a_s[kq*4+1][r] = av.y;
            a_s[kq*4+2][r] = av.z;
            a_s[kq*4+3][r] = av.w;
        }
        // B tile: 32 k x 128 cols, natural layout
        #pragma unroll
        for (int i = 0; i < 4; i++) {
            int f = tid + i * 256;
            int kk = f >> 5;
            int c4 = f & 31;
            *(float4*)&b_s[kk][c4*4] =
                *(const float4*)(Bp + (size_t)(kt + kk) * ldb + bc0 + c4 * 4);
        }
        __syncthreads();
        #pragma unroll
        for (int k = 0; k < BKK; k++) {
            float4 a0 = *(const float4*)&a_s[k][ty*4];
            float4 a1 = *(const float4*)&a_s[k][64 + ty*4];
            float4 b0 = *(const float4*)&b_s[k][tx*4];
            float4 b1 = *(const float4*)&b_s[k][64 + tx*4];
            float ar[8] = {a0.x,a0.y,a0.z,a0.w,a1.x,a1.y,a1.z,a1.w};
            float br[8] = {b0.x,b0.y,b0.z,b0.w,b1.x,b1.y,b1.z,b1.w};
            #pragma unroll
            for (int i = 0; i < 8; i++)
                #pragma unroll
                for (int j = 0; j < 8; j++)
                    acc[i][j] = fmaf(ar[i], br[j], acc[i][j]);
        }
        __syncthreads();
    }

    // Epilogue: bias, relu (q only), scatter to [B,H,N,D]
    #pragma unroll
    for (int ih = 0; ih < 2; ih++) {
        #pragma unroll
        for (int i = 0; i < 4; i++) {
            int rg = row0 + ih*64 + ty*4 + i;
            int bb = rg >> 10, nn = rg & (SEQ - 1);
            #pragma unroll
            for (int jh = 0; jh < 2; jh++) {
                int cg = bn * BN + jh*64 + tx*4;     // global col 0..1535
                float4 bias4 = (bn < 4) ? *(const float4*)(bq + cg)
                                        : *(const float4*)(bkv + cg - CDIM);
                float4 val;
                val.x = acc[ih*4+i][jh*4+0] + bias4.x;
                val.y = acc[ih*4+i][jh*4+1] + bias4.y;
                val.z = acc[ih*4+i][jh*4+2] + bias4.z;
                val.w = acc[ih*4+i][jh*4+3] + bias4.w;
                float* dst;
                if (cg < CDIM) {
                    val.x = fmaxf(val.x, 0.f); val.y = fmaxf(val.y, 0.f);
                    val.z = fmaxf(val.z, 0.f); val.w = fmaxf(val.w, 0.f);
                    int h = cg >> 6, d = cg & 63;
                    dst = q_ws + (((size_t)bb*HEADS + h)*SEQ + nn)*HD + d;
                } else {
                    int c2 = cg - CDIM;
                    int t = c2 >> 9, h = (c2 >> 6) & 7, d = c2 & 63;
                    dst = (t ? v_ws : k_ws) + (((size_t)bb*HEADS + h)*SEQ + nn)*HD + d;
                }
                *(float4*)dst = val;
            }
        }
    }
}

// ============================================================
// Kernel 2: per-(b,h) column sum of V  -> vsum[bh][64]
// ============================================================
__global__ __launch_bounds__(256) void vsum_kernel(
    const float* __restrict__ v_ws, float* __restrict__ vsum_ws)
{
    __shared__ float red[4][HD];
    const int bh = blockIdx.x;
    const int d  = threadIdx.x & 63;
    const int sl = threadIdx.x >> 6;
    const float* vh = v_ws + (size_t)bh * SEQ * HD;
    float s = 0.f;
    for (int m = sl * 256; m < (sl + 1) * 256; m++) s += vh[(size_t)m * HD + d];
    red[sl][d] = s;
    __syncthreads();
    if (threadIdx.x < HD)
        vsum_ws[(size_t)bh * HD + d] = red[0][d] + red[1][d] + red[2][d] + red[3][d];
}

// ============================================================
// Kernel 3: fused scores + exact streaming top-16 + sparse softmax + PV.
// One WG = one (b,h) and 64 query rows. Output to [B,N,H*D] layout.
//
// Math (exact): with s_i the top-16 scores, mx = max(0, max s_i),
//   Z = sum exp(s_i-mx) + (N-16) exp(-mx)
//   out = ( sum (exp(s_i-mx)-exp(-mx)) v[m_i] + exp(-mx) vsum ) / Z
// ============================================================
__global__ __launch_bounds__(256) void attn_topk_kernel(
    const float* __restrict__ q_ws, const float* __restrict__ k_ws,
    const float* __restrict__ v_ws, const float* __restrict__ vsum_ws,
    float* __restrict__ attn_out)
{
    __shared__ float q_s[64][68];
    __shared__ float k_s[64][68];
    __shared__ float s_s[64][68];
    __shared__ float w_l[64][TOPK];
    __shared__ int   i_l[64][TOPK];
    __shared__ float ez_l[64];

    const int bh = blockIdx.y;
    const int n0 = blockIdx.x * 64;
    const int tid = threadIdx.x;
    const int tx = tid & 15, ty = tid >> 4;
    const float* qh = q_ws + (size_t)bh * SEQ * HD;
    const float* kh = k_ws + (size_t)bh * SEQ * HD;
    const float* vh = v_ws + (size_t)bh * SEQ * HD;

    // load Q block 64x64
    #pragma unroll
    for (int i = 0; i < 4; i++) {
        int f = tid + i * 256;
        int r = f >> 4, dq = f & 15;
        *(float4*)&q_s[r][dq*4] = *(const float4*)(qh + (size_t)(n0 + r) * HD + dq * 4);
    }

    // streaming top-16 state (threads 0..63 each own one row)
    float tv[TOPK]; int tix[TOPK];
    #pragma unroll
    for (int t = 0; t < TOPK; t++) { tv[t] = -FLT_MAX; tix[t] = 0x7fffffff; }
    float cmin = -FLT_MAX;

    for (int mt = 0; mt < SEQ / 64; mt++) {
        __syncthreads();   // previous topk scan done before k_s/s_s overwrite
        #pragma unroll
        for (int i = 0; i < 4; i++) {
            int f = tid + i * 256;
            int r = f >> 4, dq = f & 15;
            *(float4*)&k_s[r][dq*4] =
                *(const float4*)(kh + (size_t)(mt*64 + r) * HD + dq * 4);
        }
        __syncthreads();

        // scores: rows ty*4..+3, cols tx+16*ii
        float sacc[4][4];
        #pragma unroll
        for (int i = 0; i < 4; i++)
            #pragma unroll
            for (int ii = 0; ii < 4; ii++) sacc[i][ii] = 0.f;
        #pragma unroll
        for (int dc = 0; dc < 16; dc++) {
            float4 qv[4], kv[4];
            #pragma unroll
            for (int i = 0; i < 4; i++)  qv[i] = *(const float4*)&q_s[ty*4+i][dc*4];
            #pragma unroll
            for (int ii = 0; ii < 4; ii++) kv[ii] = *(const float4*)&k_s[tx+16*ii][dc*4];
            #pragma unroll
            for (int i = 0; i < 4; i++)
                #pragma unroll
                for (int ii = 0; ii < 4; ii++) {
                    sacc[i][ii] = fmaf(qv[i].x, kv[ii].x, sacc[i][ii]);
                    sacc[i][ii] = fmaf(qv[i].y, kv[ii].y, sacc[i][ii]);
                    sacc[i][ii] = fmaf(qv[i].z, kv[ii].z, sacc[i][ii]);
                    sacc[i][ii] = fmaf(qv[i].w, kv[ii].w, sacc[i][ii]);
                }
        }
        #pragma unroll
        for (int i = 0; i < 4; i++)
            #pragma unroll
            for (int ii = 0; ii < 4; ii++)
                s_s[ty*4+i][tx+16*ii] = sacc[i][ii] * 0.125f;   // * D^-0.5
        __syncthreads();

        // top-16 scan: exact jax.lax.top_k tie order (value desc, index asc):
        // ascending-m stream + strict > + evict largest-index among min ties.
        if (tid < 64) {
            #pragma unroll 4
            for (int j = 0; j < 64; j++) {
                float val = s_s[tid][j];
                if (val > cmin) {
                    int epos = 0, ebest = -1;
                    #pragma unroll
                    for (int t = 0; t < TOPK; t++) {
                        bool is = (tv[t] == cmin) && (tix[t] > ebest);
                        if (is) { ebest = tix[t]; epos = t; }
                    }
                    #pragma unroll
                    for (int t = 0; t < TOPK; t++) {
                        if (t == epos) { tv[t] = val; tix[t] = mt*64 + j; }
                    }
                    cmin = tv[0];
                    #pragma unroll
                    for (int t = 1; t < TOPK; t++) cmin = fminf(cmin, tv[t]);
                }
            }
        }
    }
    __syncthreads();

    // finalize softmax weights per row
    if (tid < 64) {
        float tmax = tv[0];
        #pragma unroll
        for (int t = 1; t < TOPK; t++) tmax = fmaxf(tmax, tv[t]);
        float mx = fmaxf(tmax, 0.f);
        float e  = expf(-mx);
        float Z  = (float)(SEQ - TOPK) * e;
        float wexp[TOPK];
        #pragma unroll
        for (int t = 0; t < TOPK; t++) { wexp[t] = expf(tv[t] - mx); Z += wexp[t]; }
        float invZ = 1.f / Z;
        #pragma unroll
        for (int t = 0; t < TOPK; t++) {
            w_l[tid][t] = (wexp[t] - e) * invZ;
            i_l[tid][t] = tix[t];
        }
        ez_l[tid] = e * invZ;
    }
    __syncthreads();

    // PV: 4 threads per row, 16 d each
    {
        const int r = tid >> 2, dq = tid & 3, d0 = dq * 16;
        float4 acc4[4];
        float ez = ez_l[r];
        const float4* vs4 = (const float4*)(vsum_ws + (size_t)bh * HD + d0);
        #pragma unroll
        for (int j = 0; j < 4; j++) {
            float4 s = vs4[j];
            acc4[j].x = ez * s.x; acc4[j].y = ez * s.y;
            acc4[j].z = ez * s.z; acc4[j].w = ez * s.w;
        }
        #pragma unroll
        for (int t = 0; t < TOPK; t++) {
            float w = w_l[r][t];
            int m   = i_l[r][t];
            const float4* vp = (const float4*)(vh + (size_t)m * HD + d0);
            #pragma unroll
            for (int j = 0; j < 4; j++) {
                float4 vv = vp[j];
                acc4[j].x = fmaf(w, vv.x, acc4[j].x);
                acc4[j].y = fmaf(w, vv.y, acc4[j].y);
                acc4[j].z = fmaf(w, vv.z, acc4[j].z);
                acc4[j].w = fmaf(w, vv.w, acc4[j].w);
            }
        }
        const int b = bh >> 3, h = bh & 7;
        float* op = attn_out + ((size_t)(b * SEQ + n0 + r)) * CDIM + h * HD + d0;
        #pragma unroll
        for (int j = 0; j < 4; j++) ((float4*)op)[j] = acc4[j];
    }
}

// ============================================================
// Kernel 4: output projection  out = attn_out @ Wp + bp
// ============================================================
__global__ __launch_bounds__(256) void proj_gemm_kernel(
    const float* __restrict__ A,
    const float* __restrict__ Wp, const float* __restrict__ bp,
    float* __restrict__ out)
{
    __shared__ float a_s[BKK][BM + 4];
    __shared__ float b_s[BKK][BN];

    const int bm = blockIdx.x;
    const int bn = blockIdx.y;           // 0..3
    const int tid = threadIdx.x;
    const int tx = tid & 15, ty = tid >> 4;
    const int row0 = bm * BM;
    const int bc0 = bn * BN;

    float acc[8][8];
    #pragma unroll
    for (int i = 0; i < 8; i++)
        #pragma unroll
        for (int j = 0; j < 8; j++) acc[i][j] = 0.f;

    for (int kt = 0; kt < CDIM; kt += BKK) {
        #pragma unroll
        for (int i = 0; i < 4; i++) {
            int f = tid + i * 256;
            int r = f >> 3, kq = f & 7;
            float4 av = *(const float4*)(A + (size_t)(row0 + r) * CDIM + kt + kq * 4);
            a_s[kq*4+0][r] = av.x;
            a_s[kq*4+1][r] = av.y;
            a_s[kq*4+2][r] = av.z;
            a_s[kq*4+3][r] = av.w;
        }
        #pragma unroll
        for (int i = 0; i < 4; i++) {
            int f = tid + i * 256;
            int kk = f >> 5, c4 = f & 31;
            *(float4*)&b_s[kk][c4*4] =
                *(const float4*)(Wp + (size_t)(kt + kk) * CDIM + bc0 + c4 * 4);
        }
        __syncthreads();
        #pragma unroll
        for (int k = 0; k < BKK; k++) {
            float4 a0 = *(const float4*)&a_s[k][ty*4];
            float4 a1 = *(const float4*)&a_s[k][64 + ty*4];
            float4 b0 = *(const float4*)&b_s[k][tx*4];
            float4 b1 = *(const float4*)&b_s[k][64 + tx*4];
            float ar[8] = {a0.x,a0.y,a0.z,a0.w,a1.x,a1.y,a1.z,a1.w};
            float br[8] = {b0.x,b0.y,b0.z,b0.w,b1.x,b1.y,b1.z,b1.w};
            #pragma unroll
            for (int i = 0; i < 8; i++)
                #pragma unroll
                for (int j = 0; j < 8; j++)
                    acc[i][j] = fmaf(ar[i], br[j], acc[i][j]);
        }
        __syncthreads();
    }

    #pragma unroll
    for (int ih = 0; ih < 2; ih++) {
        #pragma unroll
        for (int i = 0; i < 4; i++) {
            int rg = row0 + ih*64 + ty*4 + i;
            #pragma unroll
            for (int jh = 0; jh < 2; jh++) {
                int cg = bc0 + jh*64 + tx*4;
                float4 bias4 = *(const float4*)(bp + cg);
                float4 val;
                val.x = acc[ih*4+i][jh*4+0] + bias4.x;
                val.y = acc[ih*4+i][jh*4+1] + bias4.y;
                val.z = acc[ih*4+i][jh*4+2] + bias4.z;
                val.w = acc[ih*4+i][jh*4+3] + bias4.w;
                *(float4*)(out + (size_t)rg * CDIM + cg) = val;
            }
        }
    }
}

// ============================================================
extern "C" void kernel_launch(void* const* d_in, const int* in_sizes, int n_in,
                              void* d_out, int out_size, void* d_ws, size_t ws_size,
                              hipStream_t stream)
{
    const float* x   = (const float*)d_in[0];
    const float* Wq  = (const float*)d_in[1];
    const float* bq  = (const float*)d_in[2];
    const float* Wkv = (const float*)d_in[3];
    const float* bkv = (const float*)d_in[4];
    const float* Wp  = (const float*)d_in[5];
    const float* bp  = (const float*)d_in[6];
    float* out = (float*)d_out;

    // workspace layout (floats): q | k | v | attn_out | vsum  (~64 MB)
    const size_t HSZ = (size_t)BATCH * HEADS * SEQ * HD;   // 4,194,304
    float* ws    = (float*)d_ws;
    float* q_ws  = ws;
    float* k_ws  = ws + HSZ;
    float* v_ws  = ws + 2 * HSZ;
    float* ao_ws = ws + 3 * HSZ;
    float* vs_ws = ws + 4 * HSZ;

    qkv_gemm_kernel<<<dim3(MTOT / BM, 12), 256, 0, stream>>>(
        x, Wq, bq, Wkv, bkv, q_ws, k_ws, v_ws);
    vsum_kernel<<<BATCH * HEADS, 256, 0, stream>>>(v_ws, vs_ws);
    attn_topk_kernel<<<dim3(SEQ / 64, BATCH * HEADS), 256, 0, stream>>>(
        q_ws, k_ws, v_ws, vs_ws, ao_ws);
    proj_gemm_kernel<<<dim3(MTOT / BM, CDIM / BN), 256, 0, stream>>>(
        ao_ws, Wp, bp, out);
}

// Round 2
// 756.016 us; speedup vs baseline: 1.3876x; 1.3876x over previous
//
#include <hip/hip_runtime.h>
#include <float.h>

#define BATCH 8
#define SEQ   1024
#define CDIM  512
#define HEADS 8
#define HD    64
#define TOPK  16
#define MTOT  (BATCH*SEQ)   // 8192

// ---------------- GEMM tile config ----------------
#define BM 128
#define BN 128
#define BKK 32

// ============================================================
// Kernel 1: fused QKV projection.
//   Y = x @ [Wq | Wkv] + [bq | bkv];  relu on q part.
//   Scatter to q_ws/k_ws/v_ws in [B,H,N,D] layout.
// ============================================================
__global__ __launch_bounds__(256) void qkv_gemm_kernel(
    const float* __restrict__ x,
    const float* __restrict__ Wq,  const float* __restrict__ bq,
    const float* __restrict__ Wkv, const float* __restrict__ bkv,
    float* __restrict__ q_ws, float* __restrict__ k_ws, float* __restrict__ v_ws)
{
    __shared__ float a_s[BKK][BM + 4];   // k-major (transposed) A tile, +4 pad
    __shared__ float b_s[BKK][BN];

    const int bm = blockIdx.x;           // 0..63
    const int bn = blockIdx.y;           // 0..11 (0..3 = q, 4..7 = k, 8..11 = v)
    const int tid = threadIdx.x;
    const int tx = tid & 15, ty = tid >> 4;
    const int row0 = bm * BM;

    const float* Bp; int ldb, bc0;
    if (bn < 4) { Bp = Wq;  ldb = CDIM;     bc0 = bn * BN; }
    else        { Bp = Wkv; ldb = 2 * CDIM; bc0 = bn * BN - CDIM; }

    float acc[8][8];
    #pragma unroll
    for (int i = 0; i < 8; i++)
        #pragma unroll
        for (int j = 0; j < 8; j++) acc[i][j] = 0.f;

    for (int kt = 0; kt < CDIM; kt += BKK) {
        // A tile: 128 rows x 32 k, float4 loads along k, transposed store
        #pragma unroll
        for (int i = 0; i < 4; i++) {
            int f = tid + i * 256;
            int r  = f >> 3;
            int kq = f & 7;
            float4 av = *(const float4*)(x + (size_t)(row0 + r) * CDIM + kt + kq * 4);
            a_s[kq*4+0][r] = av.x;
            a_s[kq*4+1][r] = av.y;
            a_s[kq*4+2][r] = av.z;
            a_s[kq*4+3][r] = av.w;
        }
        // B tile: 32 k x 128 cols, natural layout
        #pragma unroll
        for (int i = 0; i < 4; i++) {
            int f = tid + i * 256;
            int kk = f >> 5;
            int c4 = f & 31;
            *(float4*)&b_s[kk][c4*4] =
                *(const float4*)(Bp + (size_t)(kt + kk) * ldb + bc0 + c4 * 4);
        }
        __syncthreads();
        #pragma unroll
        for (int k = 0; k < BKK; k++) {
            float4 a0 = *(const float4*)&a_s[k][ty*4];
            float4 a1 = *(const float4*)&a_s[k][64 + ty*4];
            float4 b0 = *(const float4*)&b_s[k][tx*4];
            float4 b1 = *(const float4*)&b_s[k][64 + tx*4];
            float ar[8] = {a0.x,a0.y,a0.z,a0.w,a1.x,a1.y,a1.z,a1.w};
            float br[8] = {b0.x,b0.y,b0.z,b0.w,b1.x,b1.y,b1.z,b1.w};
            #pragma unroll
            for (int i = 0; i < 8; i++)
                #pragma unroll
                for (int j = 0; j < 8; j++)
                    acc[i][j] = fmaf(ar[i], br[j], acc[i][j]);
        }
        __syncthreads();
    }

    // Epilogue: bias, relu (q only), scatter to [B,H,N,D]
    #pragma unroll
    for (int ih = 0; ih < 2; ih++) {
        #pragma unroll
        for (int i = 0; i < 4; i++) {
            int rg = row0 + ih*64 + ty*4 + i;
            int bb = rg >> 10, nn = rg & (SEQ - 1);
            #pragma unroll
            for (int jh = 0; jh < 2; jh++) {
                int cg = bn * BN + jh*64 + tx*4;     // global col 0..1535
                float4 bias4 = (bn < 4) ? *(const float4*)(bq + cg)
                                        : *(const float4*)(bkv + cg - CDIM);
                float4 val;
                val.x = acc[ih*4+i][jh*4+0] + bias4.x;
                val.y = acc[ih*4+i][jh*4+1] + bias4.y;
                val.z = acc[ih*4+i][jh*4+2] + bias4.z;
                val.w = acc[ih*4+i][jh*4+3] + bias4.w;
                float* dst;
                if (cg < CDIM) {
                    val.x = fmaxf(val.x, 0.f); val.y = fmaxf(val.y, 0.f);
                    val.z = fmaxf(val.z, 0.f); val.w = fmaxf(val.w, 0.f);
                    int h = cg >> 6, d = cg & 63;
                    dst = q_ws + (((size_t)bb*HEADS + h)*SEQ + nn)*HD + d;
                } else {
                    int c2 = cg - CDIM;
                    int t = c2 >> 9, h = (c2 >> 6) & 7, d = c2 & 63;
                    dst = (t ? v_ws : k_ws) + (((size_t)bb*HEADS + h)*SEQ + nn)*HD + d;
                }
                *(float4*)dst = val;
            }
        }
    }
}

// ============================================================
// Kernel 2: per-(b,h) column sum of V  -> vsum[bh][64]
// ============================================================
__global__ __launch_bounds__(256) void vsum_kernel(
    const float* __restrict__ v_ws, float* __restrict__ vsum_ws)
{
    __shared__ float red[4][HD];
    const int bh = blockIdx.x;
    const int d  = threadIdx.x & 63;
    const int sl = threadIdx.x >> 6;
    const float* vh = v_ws + (size_t)bh * SEQ * HD;
    float s = 0.f;
    for (int m = sl * 256; m < (sl + 1) * 256; m++) s += vh[(size_t)m * HD + d];
    red[sl][d] = s;
    __syncthreads();
    if (threadIdx.x < HD)
        vsum_ws[(size_t)bh * HD + d] = red[0][d] + red[1][d] + red[2][d] + red[3][d];
}

// ============================================================
// Kernel 3: fused scores + PARALLEL exact streaming top-16 +
//           sparse softmax + PV.
// One WG = one (b,h) x 64 query rows, 256 threads.
//
// Parallel top-k: thread (r = tid&63, q = tid>>6) owns cols
// q*16..q*16+15 of each 64-col tile (a 256-element ascending-index
// slice over the 16 tiles). Per-thread exact streaming top-16
// (strict >, evict largest-index among min ties), then an exact
// (value desc, index asc) merge of the 4 slices per row.
//
// Math (exact): with s_i the top-16 scores, mx = max(0, max s_i),
//   Z = sum exp(s_i-mx) + (N-16) exp(-mx)
//   out = ( sum (exp(s_i-mx)-exp(-mx)) v[m_i] + exp(-mx) vsum ) / Z
// ============================================================
__global__ __launch_bounds__(256, 3) void attn_topk_kernel(
    const float* __restrict__ q_ws, const float* __restrict__ k_ws,
    const float* __restrict__ v_ws, const float* __restrict__ vsum_ws,
    float* __restrict__ attn_out)
{
    // 51456 B total -> 3 WGs/CU
    __shared__ float q_s[64][68];        // dead after last score phase
    __shared__ float k_s[64][68];        // dead after last score phase
    __shared__ float s_sT[64][65];       // [col][row]; scan reads conflict-free

    // overlays (after the tile loop):
    float* cv  = &k_s[0][0];             // cand values [r*65 + slot], 4160 fl
    int*   ci  = (int*)&q_s[0][0];       // cand indices [r*65 + slot]
    float* wl  = &s_sT[0][0];            // weights [r*16+t], 1024 fl
    int*   il  = (int*)(&s_sT[0][0] + 1024);
    float* ezl = &s_sT[0][0] + 2048;     // ez per row, 64 fl

    const int bh = blockIdx.y;
    const int n0 = blockIdx.x * 64;
    const int tid = threadIdx.x;
    const int tx = tid & 15, ty = tid >> 4;
    const int r_scan = tid & 63, q_scan = tid >> 6;
    const float* qh = q_ws + (size_t)bh * SEQ * HD;
    const float* kh = k_ws + (size_t)bh * SEQ * HD;
    const float* vh = v_ws + (size_t)bh * SEQ * HD;

    // load Q block 64x64 (persists across all K tiles)
    #pragma unroll
    for (int i = 0; i < 4; i++) {
        int f = tid + i * 256;
        int r = f >> 4, dq = f & 15;
        *(float4*)&q_s[r][dq*4] = *(const float4*)(qh + (size_t)(n0 + r) * HD + dq * 4);
    }

    // per-thread streaming top-16 over this thread's 256-col slice
    float tv[TOPK]; int tix[TOPK];
    #pragma unroll
    for (int t = 0; t < TOPK; t++) { tv[t] = -FLT_MAX; tix[t] = 0x7fffffff; }
    float cmin = -FLT_MAX;

    for (int mt = 0; mt < SEQ / 64; mt++) {
        // 1. prefetch K tile into registers (latency hidden behind scan)
        float4 kreg[4];
        #pragma unroll
        for (int i = 0; i < 4; i++) {
            int f = tid + i * 256;
            int r = f >> 4, dq = f & 15;
            kreg[i] = *(const float4*)(kh + (size_t)(mt*64 + r) * HD + dq * 4);
        }

        // 2. scan previous tile's scores (reads s_sT; all 256 threads)
        if (mt > 0) {
            #pragma unroll
            for (int j = 0; j < 16; j++) {
                float val = s_sT[q_scan*16 + j][r_scan];
                if (val > cmin) {
                    int epos = 0, ebest = -1;
                    #pragma unroll
                    for (int t = 0; t < TOPK; t++) {
                        bool is = (tv[t] == cmin) && (tix[t] > ebest);
                        if (is) { ebest = tix[t]; epos = t; }
                    }
                    int newidx = (mt-1)*64 + q_scan*16 + j;
                    #pragma unroll
                    for (int t = 0; t < TOPK; t++) {
                        if (t == epos) { tv[t] = val; tix[t] = newidx; }
                    }
                    cmin = tv[0];
                    #pragma unroll
                    for (int t = 1; t < TOPK; t++) cmin = fminf(cmin, tv[t]);
                }
            }
        }

        // 3. write K tile to LDS (k_s not read since last barrier)
        #pragma unroll
        for (int i = 0; i < 4; i++) {
            int f = tid + i * 256;
            int r = f >> 4, dq = f & 15;
            *(float4*)&k_s[r][dq*4] = kreg[i];
        }
        __syncthreads();   // k_s visible; all scans of s_sT done

        // 4. scores: rows ty*4..+3, cols tx+16*ii -> s_sT[col][row]
        float sacc[4][4];
        #pragma unroll
        for (int i = 0; i < 4; i++)
            #pragma unroll
            for (int ii = 0; ii < 4; ii++) sacc[i][ii] = 0.f;
        #pragma unroll
        for (int dc = 0; dc < 16; dc++) {
            float4 qv[4], kv[4];
            #pragma unroll
            for (int i = 0; i < 4; i++)  qv[i] = *(const float4*)&q_s[ty*4+i][dc*4];
            #pragma unroll
            for (int ii = 0; ii < 4; ii++) kv[ii] = *(const float4*)&k_s[tx+16*ii][dc*4];
            #pragma unroll
            for (int i = 0; i < 4; i++)
                #pragma unroll
                for (int ii = 0; ii < 4; ii++) {
                    sacc[i][ii] = fmaf(qv[i].x, kv[ii].x, sacc[i][ii]);
                    sacc[i][ii] = fmaf(qv[i].y, kv[ii].y, sacc[i][ii]);
                    sacc[i][ii] = fmaf(qv[i].z, kv[ii].z, sacc[i][ii]);
                    sacc[i][ii] = fmaf(qv[i].w, kv[ii].w, sacc[i][ii]);
                }
        }
        #pragma unroll
        for (int i = 0; i < 4; i++)
            #pragma unroll
            for (int ii = 0; ii < 4; ii++)
                s_sT[tx+16*ii][ty*4+i] = sacc[i][ii] * 0.125f;   // * D^-0.5
        __syncthreads();   // s_sT visible for scan
    }

    // scan last tile
    {
        const int mt = SEQ / 64;
        #pragma unroll
        for (int j = 0; j < 16; j++) {
            float val = s_sT[q_scan*16 + j][r_scan];
            if (val > cmin) {
                int epos = 0, ebest = -1;
                #pragma unroll
                for (int t = 0; t < TOPK; t++) {
                    bool is = (tv[t] == cmin) && (tix[t] > ebest);
                    if (is) { ebest = tix[t]; epos = t; }
                }
                int newidx = (mt-1)*64 + q_scan*16 + j;
                #pragma unroll
                for (int t = 0; t < TOPK; t++) {
                    if (t == epos) { tv[t] = val; tix[t] = newidx; }
                }
                cmin = tv[0];
                #pragma unroll
                for (int t = 1; t < TOPK; t++) cmin = fminf(cmin, tv[t]);
            }
        }
    }
    __syncthreads();   // scans done: q_s/k_s/s_sT regions now reusable

    // write candidates: values -> k_s region, indices -> q_s region
    #pragma unroll
    for (int t = 0; t < TOPK; t++) {
        cv[r_scan*65 + q_scan*16 + t] = tv[t];
        ci[r_scan*65 + q_scan*16 + t] = tix[t];
    }
    __syncthreads();

    // merge 4x16 -> exact global top-16 per row; finalize softmax weights
    if (tid < 64) {
        float mv[TOPK]; int mi[TOPK];
        #pragma unroll
        for (int t = 0; t < TOPK; t++) { mv[t] = -FLT_MAX; mi[t] = 0x7fffffff; }
        float wv = -FLT_MAX; int wi = 0x7fffffff; int wpos = 0;
        for (int j = 0; j < 64; j++) {
            float v = cv[tid*65 + j];
            int   id = ci[tid*65 + j];
            if (v > wv || (v == wv && id < wi)) {
                #pragma unroll
                for (int t = 0; t < TOPK; t++) {
                    if (t == wpos) { mv[t] = v; mi[t] = id; }
                }
                // recompute worst: min value, tie -> largest index
                wv = mv[0]; wi = mi[0]; wpos = 0;
                #pragma unroll
                for (int t = 1; t < TOPK; t++) {
                    bool worse = (mv[t] < wv) || (mv[t] == wv && mi[t] > wi);
                    if (worse) { wv = mv[t]; wi = mi[t]; wpos = t; }
                }
            }
        }
        float tmax = mv[0];
        #pragma unroll
        for (int t = 1; t < TOPK; t++) tmax = fmaxf(tmax, mv[t]);
        float mx = fmaxf(tmax, 0.f);
        float e  = expf(-mx);
        float Z  = (float)(SEQ - TOPK) * e;
        float wexp[TOPK];
        #pragma unroll
        for (int t = 0; t < TOPK; t++) { wexp[t] = expf(mv[t] - mx); Z += wexp[t]; }
        float invZ = 1.f / Z;
        #pragma unroll
        for (int t = 0; t < TOPK; t++) {
            wl[tid*16 + t] = (wexp[t] - e) * invZ;
            il[tid*16 + t] = mi[t];
        }
        ezl[tid] = e * invZ;
    }
    __syncthreads();

    // PV: 4 threads per row, 16 d each
    {
        const int r = tid >> 2, dq = tid & 3, d0 = dq * 16;
        float4 acc4[4];
        float ez = ezl[r];
        const float4* vs4 = (const float4*)(vsum_ws + (size_t)bh * HD + d0);
        #pragma unroll
        for (int j = 0; j < 4; j++) {
            float4 s = vs4[j];
            acc4[j].x = ez * s.x; acc4[j].y = ez * s.y;
            acc4[j].z = ez * s.z; acc4[j].w = ez * s.w;
        }
        #pragma unroll
        for (int t = 0; t < TOPK; t++) {
            float w = wl[r*16 + t];
            int m   = il[r*16 + t];
            const float4* vp = (const float4*)(vh + (size_t)m * HD + d0);
            #pragma unroll
            for (int j = 0; j < 4; j++) {
                float4 vv = vp[j];
                acc4[j].x = fmaf(w, vv.x, acc4[j].x);
                acc4[j].y = fmaf(w, vv.y, acc4[j].y);
                acc4[j].z = fmaf(w, vv.z, acc4[j].z);
                acc4[j].w = fmaf(w, vv.w, acc4[j].w);
            }
        }
        const int b = bh >> 3, h = bh & 7;
        float* op = attn_out + ((size_t)(b * SEQ + n0 + r)) * CDIM + h * HD + d0;
        #pragma unroll
        for (int j = 0; j < 4; j++) ((float4*)op)[j] = acc4[j];
    }
}

// ============================================================
// Kernel 4: output projection  out = attn_out @ Wp + bp
// ============================================================
__global__ __launch_bounds__(256) void proj_gemm_kernel(
    const float* __restrict__ A,
    const float* __restrict__ Wp, const float* __restrict__ bp,
    float* __restrict__ out)
{
    __shared__ float a_s[BKK][BM + 4];
    __shared__ float b_s[BKK][BN];

    const int bm = blockIdx.x;
    const int bn = blockIdx.y;           // 0..3
    const int tid = threadIdx.x;
    const int tx = tid & 15, ty = tid >> 4;
    const int row0 = bm * BM;
    const int bc0 = bn * BN;

    float acc[8][8];
    #pragma unroll
    for (int i = 0; i < 8; i++)
        #pragma unroll
        for (int j = 0; j < 8; j++) acc[i][j] = 0.f;

    for (int kt = 0; kt < CDIM; kt += BKK) {
        #pragma unroll
        for (int i = 0; i < 4; i++) {
            int f = tid + i * 256;
            int r = f >> 3, kq = f & 7;
            float4 av = *(const float4*)(A + (size_t)(row0 + r) * CDIM + kt + kq * 4);
            a_s[kq*4+0][r] = av.x;
            a_s[kq*4+1][r] = av.y;
            a_s[kq*4+2][r] = av.z;
            a_s[kq*4+3][r] = av.w;
        }
        #pragma unroll
        for (int i = 0; i < 4; i++) {
            int f = tid + i * 256;
            int kk = f >> 5, c4 = f & 31;
            *(float4*)&b_s[kk][c4*4] =
                *(const float4*)(Wp + (size_t)(kt + kk) * CDIM + bc0 + c4 * 4);
        }
        __syncthreads();
        #pragma unroll
        for (int k = 0; k < BKK; k++) {
            float4 a0 = *(const float4*)&a_s[k][ty*4];
            float4 a1 = *(const float4*)&a_s[k][64 + ty*4];
            float4 b0 = *(const float4*)&b_s[k][tx*4];
            float4 b1 = *(const float4*)&b_s[k][64 + tx*4];
            float ar[8] = {a0.x,a0.y,a0.z,a0.w,a1.x,a1.y,a1.z,a1.w};
            float br[8] = {b0.x,b0.y,b0.z,b0.w,b1.x,b1.y,b1.z,b1.w};
            #pragma unroll
            for (int i = 0; i < 8; i++)
                #pragma unroll
                for (int j = 0; j < 8; j++)
                    acc[i][j] = fmaf(ar[i], br[j], acc[i][j]);
        }
        __syncthreads();
    }

    #pragma unroll
    for (int ih = 0; ih < 2; ih++) {
        #pragma unroll
        for (int i = 0; i < 4; i++) {
            int rg = row0 + ih*64 + ty*4 + i;
            #pragma unroll
            for (int jh = 0; jh < 2; jh++) {
                int cg = bc0 + jh*64 + tx*4;
                float4 bias4 = *(const float4*)(bp + cg);
                float4 val;
                val.x = acc[ih*4+i][jh*4+0] + bias4.x;
                val.y = acc[ih*4+i][jh*4+1] + bias4.y;
                val.z = acc[ih*4+i][jh*4+2] + bias4.z;
                val.w = acc[ih*4+i][jh*4+3] + bias4.w;
                *(float4*)(out + (size_t)rg * CDIM + cg) = val;
            }
        }
    }
}

// ============================================================
extern "C" void kernel_launch(void* const* d_in, const int* in_sizes, int n_in,
                              void* d_out, int out_size, void* d_ws, size_t ws_size,
                              hipStream_t stream)
{
    const float* x   = (const float*)d_in[0];
    const float* Wq  = (const float*)d_in[1];
    const float* bq  = (const float*)d_in[2];
    const float* Wkv = (const float*)d_in[3];
    const float* bkv = (const float*)d_in[4];
    const float* Wp  = (const float*)d_in[5];
    const float* bp  = (const float*)d_in[6];
    float* out = (float*)d_out;

    // workspace layout (floats): q | k | v | attn_out | vsum  (~64 MB)
    const size_t HSZ = (size_t)BATCH * HEADS * SEQ * HD;   // 4,194,304
    float* ws    = (float*)d_ws;
    float* q_ws  = ws;
    float* k_ws  = ws + HSZ;
    float* v_ws  = ws + 2 * HSZ;
    float* ao_ws = ws + 3 * HSZ;
    float* vs_ws = ws + 4 * HSZ;

    qkv_gemm_kernel<<<dim3(MTOT / BM, 12), 256, 0, stream>>>(
        x, Wq, bq, Wkv, bkv, q_ws, k_ws, v_ws);
    vsum_kernel<<<BATCH * HEADS, 256, 0, stream>>>(v_ws, vs_ws);
    attn_topk_kernel<<<dim3(SEQ / 64, BATCH * HEADS), 256, 0, stream>>>(
        q_ws, k_ws, v_ws, vs_ws, ao_ws);
    proj_gemm_kernel<<<dim3(MTOT / BM, CDIM / BN), 256, 0, stream>>>(
        ao_ws, Wp, bp, out);
}

// Round 3
// 675.749 us; speedup vs baseline: 1.5524x; 1.1188x over previous
//
#include <hip/hip_runtime.h>
#include <float.h>

#define BATCH 8
#define SEQ   1024
#define CDIM  512
#define HEADS 8
#define HD    64
#define TOPK  16
#define MTOT  (BATCH*SEQ)   // 8192

// ---------------- GEMM tile config ----------------
#define BM 128
#define BN 128
#define BKK 32

typedef short bf16x8 __attribute__((ext_vector_type(8)));
typedef float f32x4v __attribute__((ext_vector_type(4)));

// round-to-nearest bf16 split: f = hi + lo, each bf16; |err| ~ 2^-17 |f|
__device__ inline void bf16split(float f, unsigned short& h, unsigned short& l) {
    unsigned u = __float_as_uint(f);
    unsigned hr = (u + 0x7fffu + ((u >> 16) & 1u)) >> 16;
    h = (unsigned short)hr;
    float rest = f - __uint_as_float(hr << 16);
    unsigned v = __float_as_uint(rest);
    l = (unsigned short)((v + 0x7fffu + ((v >> 16) & 1u)) >> 16);
}

// ============================================================
// Kernel 1: fused QKV projection (fp32 core).
//   Epilogue: relu(q); split q,k into bf16 hi/lo planes; v stays fp32.
// ============================================================
__global__ __launch_bounds__(256) void qkv_gemm_kernel(
    const float* __restrict__ x,
    const float* __restrict__ Wq,  const float* __restrict__ bq,
    const float* __restrict__ Wkv, const float* __restrict__ bkv,
    unsigned short* __restrict__ qhi_g, unsigned short* __restrict__ qlo_g,
    unsigned short* __restrict__ khi_g, unsigned short* __restrict__ klo_g,
    float* __restrict__ v_ws)
{
    __shared__ float a_s[BKK][BM + 4];
    __shared__ float b_s[BKK][BN];

    const int bm = blockIdx.x;
    const int bn = blockIdx.y;           // 0..11 (0..3 q, 4..7 k, 8..11 v)
    const int tid = threadIdx.x;
    const int tx = tid & 15, ty = tid >> 4;
    const int row0 = bm * BM;

    const float* Bp; int ldb, bc0;
    if (bn < 4) { Bp = Wq;  ldb = CDIM;     bc0 = bn * BN; }
    else        { Bp = Wkv; ldb = 2 * CDIM; bc0 = bn * BN - CDIM; }

    float acc[8][8];
    #pragma unroll
    for (int i = 0; i < 8; i++)
        #pragma unroll
        for (int j = 0; j < 8; j++) acc[i][j] = 0.f;

    for (int kt = 0; kt < CDIM; kt += BKK) {
        #pragma unroll
        for (int i = 0; i < 4; i++) {
            int f = tid + i * 256;
            int r  = f >> 3, kq = f & 7;
            float4 av = *(const float4*)(x + (size_t)(row0 + r) * CDIM + kt + kq * 4);
            a_s[kq*4+0][r] = av.x; a_s[kq*4+1][r] = av.y;
            a_s[kq*4+2][r] = av.z; a_s[kq*4+3][r] = av.w;
        }
        #pragma unroll
        for (int i = 0; i < 4; i++) {
            int f = tid + i * 256;
            int kk = f >> 5, c4 = f & 31;
            *(float4*)&b_s[kk][c4*4] =
                *(const float4*)(Bp + (size_t)(kt + kk) * ldb + bc0 + c4 * 4);
        }
        __syncthreads();
        #pragma unroll
        for (int k = 0; k < BKK; k++) {
            float4 a0 = *(const float4*)&a_s[k][ty*4];
            float4 a1 = *(const float4*)&a_s[k][64 + ty*4];
            float4 b0 = *(const float4*)&b_s[k][tx*4];
            float4 b1 = *(const float4*)&b_s[k][64 + tx*4];
            float ar[8] = {a0.x,a0.y,a0.z,a0.w,a1.x,a1.y,a1.z,a1.w};
            float br[8] = {b0.x,b0.y,b0.z,b0.w,b1.x,b1.y,b1.z,b1.w};
            #pragma unroll
            for (int i = 0; i < 8; i++)
                #pragma unroll
                for (int j = 0; j < 8; j++)
                    acc[i][j] = fmaf(ar[i], br[j], acc[i][j]);
        }
        __syncthreads();
    }

    #pragma unroll
    for (int ih = 0; ih < 2; ih++) {
        #pragma unroll
        for (int i = 0; i < 4; i++) {
            int rg = row0 + ih*64 + ty*4 + i;
            int bb = rg >> 10, nn = rg & (SEQ - 1);
            #pragma unroll
            for (int jh = 0; jh < 2; jh++) {
                int cg = bn * BN + jh*64 + tx*4;
                float4 bias4 = (bn < 4) ? *(const float4*)(bq + cg)
                                        : *(const float4*)(bkv + cg - CDIM);
                float4 val;
                val.x = acc[ih*4+i][jh*4+0] + bias4.x;
                val.y = acc[ih*4+i][jh*4+1] + bias4.y;
                val.z = acc[ih*4+i][jh*4+2] + bias4.z;
                val.w = acc[ih*4+i][jh*4+3] + bias4.w;
                if (cg < CDIM) {
                    val.x = fmaxf(val.x, 0.f); val.y = fmaxf(val.y, 0.f);
                    val.z = fmaxf(val.z, 0.f); val.w = fmaxf(val.w, 0.f);
                    int h = cg >> 6, d = cg & 63;
                    size_t base = (((size_t)bb*HEADS + h)*SEQ + nn)*HD + d;
                    ushort4 hv, lv;
                    bf16split(val.x, hv.x, lv.x); bf16split(val.y, hv.y, lv.y);
                    bf16split(val.z, hv.z, lv.z); bf16split(val.w, hv.w, lv.w);
                    *(ushort4*)(qhi_g + base) = hv;
                    *(ushort4*)(qlo_g + base) = lv;
                } else {
                    int c2 = cg - CDIM;
                    int t = c2 >> 9, h = (c2 >> 6) & 7, d = c2 & 63;
                    size_t base = (((size_t)bb*HEADS + h)*SEQ + nn)*HD + d;
                    if (t == 0) {
                        ushort4 hv, lv;
                        bf16split(val.x, hv.x, lv.x); bf16split(val.y, hv.y, lv.y);
                        bf16split(val.z, hv.z, lv.z); bf16split(val.w, hv.w, lv.w);
                        *(ushort4*)(khi_g + base) = hv;
                        *(ushort4*)(klo_g + base) = lv;
                    } else {
                        *(float4*)(v_ws + base) = val;
                    }
                }
            }
        }
    }
}

// ============================================================
// Kernel 2: per-(b,h) column sum of V  -> vsum[bh][64]
// ============================================================
__global__ __launch_bounds__(256) void vsum_kernel(
    const float* __restrict__ v_ws, float* __restrict__ vsum_ws)
{
    __shared__ float red[4][HD];
    const int bh = blockIdx.x;
    const int d  = threadIdx.x & 63;
    const int sl = threadIdx.x >> 6;
    const float* vh = v_ws + (size_t)bh * SEQ * HD;
    float s = 0.f;
    for (int m = sl * 256; m < (sl + 1) * 256; m++) s += vh[(size_t)m * HD + d];
    red[sl][d] = s;
    __syncthreads();
    if (threadIdx.x < HD)
        vsum_ws[(size_t)bh * HD + d] = red[0][d] + red[1][d] + red[2][d] + red[3][d];
}

// ============================================================
// Kernel 3: MFMA split-bf16 scores + parallel exact top-16 +
//           sparse softmax + PV.
// Scores via mfma_f32_16x16x32_bf16: S = Qhi*Khi + Qhi*Klo + Qlo*Khi.
// LDS tiles stored in fragment order (16B chunk per lane) so every
// fragment load is one contiguous ds_read_b128 (conflict-free).
// Chunk map: chunk(tile ct, khalf h, lane) = ((ct*2+h)*64 + lane)*8 shorts,
// content = T[ct*16 + (lane&15)][h*32 + (lane>>4)*8 .. +8].
// ============================================================
__global__ __launch_bounds__(256, 3) void attn_topk_kernel(
    const unsigned short* __restrict__ qhi_g, const unsigned short* __restrict__ qlo_g,
    const unsigned short* __restrict__ khi_g, const unsigned short* __restrict__ klo_g,
    const float* __restrict__ v_ws, const float* __restrict__ vsum_ws,
    float* __restrict__ attn_out)
{
    // 49408 B -> 3 blocks/CU
    __shared__ __align__(16) char smem[49408];
    short* qhi_s = (short*)smem;              //  8192 B
    short* qlo_s = (short*)(smem + 8192);     //  8192 B
    short* khi_s = (short*)(smem + 16384);    //  8192 B
    short* klo_s = (short*)(smem + 24576);    //  8192 B
    float* s_sT  = (float*)(smem + 32768);    // 64x65 fl = 16640 B

    // overlays (after tile loop; Q/K tiles and s_sT dead):
    float* cv  = s_sT;                        // 16640 B
    int*   ci  = (int*)smem;                  // 16640 B (spans Q + 256B of K)
    float* wl  = (float*)(smem + 16640);      //  4096 B
    int*   il  = (int*)(smem + 20736);        //  4096 B
    float* ezl = (float*)(smem + 24832);      //   256 B

    const int bh = blockIdx.y;
    const int n0 = blockIdx.x * 64;
    const int tid = threadIdx.x;
    const int lane = tid & 63, w = tid >> 6;
    const int r_st = tid >> 2, c4 = tid & 3;      // staging: row, 16-col segment
    const int r_scan = tid & 63, q_scan = tid >> 6;
    const size_t hb = (size_t)bh * SEQ * HD;
    const float* vh = v_ws + hb;

    // staging chunk indices for (row r_st, 8-col segments s0, s0+1)
    const int s0 = c4 * 2, s1 = s0 + 1;
    const int cx0 = ((r_st >> 4)*2 + (s0 >> 2))*64 + (s0 & 3)*16 + (r_st & 15);
    const int cx1 = ((r_st >> 4)*2 + (s1 >> 2))*64 + (s1 & 3)*16 + (r_st & 15);

    // ---- stage Q tile (fragment order) ----
    {
        const unsigned short* qp  = qhi_g + hb + (size_t)(n0 + r_st)*HD + c4*16;
        const unsigned short* qp2 = qlo_g + hb + (size_t)(n0 + r_st)*HD + c4*16;
        uint4 h0 = *(const uint4*)qp,  h1 = *(const uint4*)(qp + 8);
        uint4 l0 = *(const uint4*)qp2, l1 = *(const uint4*)(qp2 + 8);
        *(uint4*)&qhi_s[cx0*8] = h0; *(uint4*)&qhi_s[cx1*8] = h1;
        *(uint4*)&qlo_s[cx0*8] = l0; *(uint4*)&qlo_s[cx1*8] = l1;
    }
    __syncthreads();
    // Q fragments held in registers for the whole tile loop
    bf16x8 qh[2], ql[2];
    #pragma unroll
    for (int h = 0; h < 2; h++) {
        qh[h] = *(bf16x8*)&qhi_s[((w*2 + h)*64 + lane)*8];
        ql[h] = *(bf16x8*)&qlo_s[((w*2 + h)*64 + lane)*8];
    }

    // per-thread streaming top-16 over this thread's 256-col slice
    float tv[TOPK]; int tix[TOPK];
    #pragma unroll
    for (int t = 0; t < TOPK; t++) { tv[t] = -FLT_MAX; tix[t] = 0x7fffffff; }
    float cmin = -FLT_MAX;

    for (int mt = 0; mt < SEQ / 64; mt++) {
        // 1. prefetch K tile (global, packed hi/lo planes)
        const unsigned short* kp  = khi_g + hb + (size_t)(mt*64 + r_st)*HD + c4*16;
        const unsigned short* kp2 = klo_g + hb + (size_t)(mt*64 + r_st)*HD + c4*16;
        uint4 kh0 = *(const uint4*)kp,  kh1 = *(const uint4*)(kp + 8);
        uint4 kl0 = *(const uint4*)kp2, kl1 = *(const uint4*)(kp2 + 8);

        // 2. scan previous tile's scores
        if (mt > 0) {
            #pragma unroll
            for (int j = 0; j < 16; j++) {
                float val = s_sT[(q_scan*16 + j)*65 + r_scan];
                if (val > cmin) {
                    int epos = 0, ebest = -1;
                    #pragma unroll
                    for (int t = 0; t < TOPK; t++) {
                        bool is = (tv[t] == cmin) && (tix[t] > ebest);
                        if (is) { ebest = tix[t]; epos = t; }
                    }
                    int newidx = (mt-1)*64 + q_scan*16 + j;
                    #pragma unroll
                    for (int t = 0; t < TOPK; t++) {
                        if (t == epos) { tv[t] = val; tix[t] = newidx; }
                    }
                    cmin = tv[0];
                    #pragma unroll
                    for (int t = 1; t < TOPK; t++) cmin = fminf(cmin, tv[t]);
                }
            }
        }

        // 3. write K tile to LDS (fragment order)
        *(uint4*)&khi_s[cx0*8] = kh0; *(uint4*)&khi_s[cx1*8] = kh1;
        *(uint4*)&klo_s[cx0*8] = kl0; *(uint4*)&klo_s[cx1*8] = kl1;
        __syncthreads();

        // 4. MFMA scores: wave w -> S rows w*16..+15, 4 col-tiles
        #pragma unroll
        for (int ct = 0; ct < 4; ct++) {
            f32x4v acc = {0.f, 0.f, 0.f, 0.f};
            #pragma unroll
            for (int h = 0; h < 2; h++) {
                bf16x8 kh = *(bf16x8*)&khi_s[((ct*2 + h)*64 + lane)*8];
                bf16x8 kl = *(bf16x8*)&klo_s[((ct*2 + h)*64 + lane)*8];
                acc = __builtin_amdgcn_mfma_f32_16x16x32_bf16(qh[h], kh, acc, 0, 0, 0);
                acc = __builtin_amdgcn_mfma_f32_16x16x32_bf16(qh[h], kl, acc, 0, 0, 0);
                acc = __builtin_amdgcn_mfma_f32_16x16x32_bf16(ql[h], kh, acc, 0, 0, 0);
            }
            // C/D: col = lane&15, row = (lane>>4)*4 + reg  (m89/m91-verified)
            int col  = ct*16 + (lane & 15);
            int rowb = w*16 + (lane >> 4)*4;
            #pragma unroll
            for (int rg = 0; rg < 4; rg++)
                s_sT[col*65 + rowb + rg] = acc[rg] * 0.125f;   // * D^-0.5
        }
        __syncthreads();
    }

    // scan last tile
    {
        const int mt = SEQ / 64;
        #pragma unroll
        for (int j = 0; j < 16; j++) {
            float val = s_sT[(q_scan*16 + j)*65 + r_scan];
            if (val > cmin) {
                int epos = 0, ebest = -1;
                #pragma unroll
                for (int t = 0; t < TOPK; t++) {
                    bool is = (tv[t] == cmin) && (tix[t] > ebest);
                    if (is) { ebest = tix[t]; epos = t; }
                }
                int newidx = (mt-1)*64 + q_scan*16 + j;
                #pragma unroll
                for (int t = 0; t < TOPK; t++) {
                    if (t == epos) { tv[t] = val; tix[t] = newidx; }
                }
                cmin = tv[0];
                #pragma unroll
                for (int t = 1; t < TOPK; t++) cmin = fminf(cmin, tv[t]);
            }
        }
    }
    __syncthreads();   // scans done; overlay regions now safe

    // write candidates
    #pragma unroll
    for (int t = 0; t < TOPK; t++) {
        cv[r_scan*65 + q_scan*16 + t] = tv[t];
        ci[r_scan*65 + q_scan*16 + t] = tix[t];
    }
    __syncthreads();

    // merge 4x16 -> exact global top-16 per row (value desc, index asc)
    if (tid < 64) {
        float mv[TOPK]; int mi[TOPK];
        #pragma unroll
        for (int t = 0; t < TOPK; t++) { mv[t] = -FLT_MAX; mi[t] = 0x7fffffff; }
        float wv = -FLT_MAX; int wi = 0x7fffffff; int wpos = 0;
        for (int j = 0; j < 64; j++) {
            float v = cv[tid*65 + j];
            int   id = ci[tid*65 + j];
            if (v > wv || (v == wv && id < wi)) {
                #pragma unroll
                for (int t = 0; t < TOPK; t++) {
                    if (t == wpos) { mv[t] = v; mi[t] = id; }
                }
                wv = mv[0]; wi = mi[0]; wpos = 0;
                #pragma unroll
                for (int t = 1; t < TOPK; t++) {
                    bool worse = (mv[t] < wv) || (mv[t] == wv && mi[t] > wi);
                    if (worse) { wv = mv[t]; wi = mi[t]; wpos = t; }
                }
            }
        }
        float tmax = mv[0];
        #pragma unroll
        for (int t = 1; t < TOPK; t++) tmax = fmaxf(tmax, mv[t]);
        float mx = fmaxf(tmax, 0.f);
        float e  = expf(-mx);
        float Z  = (float)(SEQ - TOPK) * e;
        float wexp[TOPK];
        #pragma unroll
        for (int t = 0; t < TOPK; t++) { wexp[t] = expf(mv[t] - mx); Z += wexp[t]; }
        float invZ = 1.f / Z;
        #pragma unroll
        for (int t = 0; t < TOPK; t++) {
            wl[tid*16 + t] = (wexp[t] - e) * invZ;
            il[tid*16 + t] = mi[t];
        }
        ezl[tid] = e * invZ;
    }
    __syncthreads();

    // PV: 4 threads per row, 16 d each
    {
        const int r = tid >> 2, dq = tid & 3, d0 = dq * 16;
        float4 acc4[4];
        float ez = ezl[r];
        const float4* vs4 = (const float4*)(vsum_ws + (size_t)bh * HD + d0);
        #pragma unroll
        for (int j = 0; j < 4; j++) {
            float4 s = vs4[j];
            acc4[j].x = ez * s.x; acc4[j].y = ez * s.y;
            acc4[j].z = ez * s.z; acc4[j].w = ez * s.w;
        }
        #pragma unroll
        for (int t = 0; t < TOPK; t++) {
            float wgt = wl[r*16 + t];
            int m   = il[r*16 + t];
            const float4* vp = (const float4*)(vh + (size_t)m * HD + d0);
            #pragma unroll
            for (int j = 0; j < 4; j++) {
                float4 vv = vp[j];
                acc4[j].x = fmaf(wgt, vv.x, acc4[j].x);
                acc4[j].y = fmaf(wgt, vv.y, acc4[j].y);
                acc4[j].z = fmaf(wgt, vv.z, acc4[j].z);
                acc4[j].w = fmaf(wgt, vv.w, acc4[j].w);
            }
        }
        const int b = bh >> 3, h = bh & 7;
        float* op = attn_out + ((size_t)(b * SEQ + n0 + r)) * CDIM + h * HD + d0;
        #pragma unroll
        for (int j = 0; j < 4; j++) ((float4*)op)[j] = acc4[j];
    }
}

// ============================================================
// Kernel 4: output projection  out = attn_out @ Wp + bp
// ============================================================
__global__ __launch_bounds__(256) void proj_gemm_kernel(
    const float* __restrict__ A,
    const float* __restrict__ Wp, const float* __restrict__ bp,
    float* __restrict__ out)
{
    __shared__ float a_s[BKK][BM + 4];
    __shared__ float b_s[BKK][BN];

    const int bm = blockIdx.x;
    const int bn = blockIdx.y;
    const int tid = threadIdx.x;
    const int tx = tid & 15, ty = tid >> 4;
    const int row0 = bm * BM;
    const int bc0 = bn * BN;

    float acc[8][8];
    #pragma unroll
    for (int i = 0; i < 8; i++)
        #pragma unroll
        for (int j = 0; j < 8; j++) acc[i][j] = 0.f;

    for (int kt = 0; kt < CDIM; kt += BKK) {
        #pragma unroll
        for (int i = 0; i < 4; i++) {
            int f = tid + i * 256;
            int r = f >> 3, kq = f & 7;
            float4 av = *(const float4*)(A + (size_t)(row0 + r) * CDIM + kt + kq * 4);
            a_s[kq*4+0][r] = av.x; a_s[kq*4+1][r] = av.y;
            a_s[kq*4+2][r] = av.z; a_s[kq*4+3][r] = av.w;
        }
        #pragma unroll
        for (int i = 0; i < 4; i++) {
            int f = tid + i * 256;
            int kk = f >> 5, c4 = f & 31;
            *(float4*)&b_s[kk][c4*4] =
                *(const float4*)(Wp + (size_t)(kt + kk) * CDIM + bc0 + c4 * 4);
        }
        __syncthreads();
        #pragma unroll
        for (int k = 0; k < BKK; k++) {
            float4 a0 = *(const float4*)&a_s[k][ty*4];
            float4 a1 = *(const float4*)&a_s[k][64 + ty*4];
            float4 b0 = *(const float4*)&b_s[k][tx*4];
            float4 b1 = *(const float4*)&b_s[k][64 + tx*4];
            float ar[8] = {a0.x,a0.y,a0.z,a0.w,a1.x,a1.y,a1.z,a1.w};
            float br[8] = {b0.x,b0.y,b0.z,b0.w,b1.x,b1.y,b1.z,b1.w};
            #pragma unroll
            for (int i = 0; i < 8; i++)
                #pragma unroll
                for (int j = 0; j < 8; j++)
                    acc[i][j] = fmaf(ar[i], br[j], acc[i][j]);
        }
        __syncthreads();
    }

    #pragma unroll
    for (int ih = 0; ih < 2; ih++) {
        #pragma unroll
        for (int i = 0; i < 4; i++) {
            int rg = row0 + ih*64 + ty*4 + i;
            #pragma unroll
            for (int jh = 0; jh < 2; jh++) {
                int cg = bc0 + jh*64 + tx*4;
                float4 bias4 = *(const float4*)(bp + cg);
                float4 val;
                val.x = acc[ih*4+i][jh*4+0] + bias4.x;
                val.y = acc[ih*4+i][jh*4+1] + bias4.y;
                val.z = acc[ih*4+i][jh*4+2] + bias4.z;
                val.w = acc[ih*4+i][jh*4+3] + bias4.w;
                *(float4*)(out + (size_t)rg * CDIM + cg) = val;
            }
        }
    }
}

// ============================================================
extern "C" void kernel_launch(void* const* d_in, const int* in_sizes, int n_in,
                              void* d_out, int out_size, void* d_ws, size_t ws_size,
                              hipStream_t stream)
{
    const float* x   = (const float*)d_in[0];
    const float* Wq  = (const float*)d_in[1];
    const float* bq  = (const float*)d_in[2];
    const float* Wkv = (const float*)d_in[3];
    const float* bkv = (const float*)d_in[4];
    const float* Wp  = (const float*)d_in[5];
    const float* bp  = (const float*)d_in[6];
    float* out = (float*)d_out;

    // workspace (floats): v | ao | vsum | then 4 ushort planes (qhi,qlo,khi,klo)
    const size_t HSZ = (size_t)BATCH * HEADS * SEQ * HD;   // 4,194,304
    float* ws    = (float*)d_ws;
    float* v_ws  = ws;
    float* ao_ws = ws + HSZ;
    float* vs_ws = ws + 2 * HSZ;                      // 4096 floats
    unsigned short* qhi_g = (unsigned short*)(ws + 2 * HSZ + 4096);
    unsigned short* qlo_g = qhi_g + HSZ;
    unsigned short* khi_g = qhi_g + 2 * HSZ;
    unsigned short* klo_g = qhi_g + 3 * HSZ;

    qkv_gemm_kernel<<<dim3(MTOT / BM, 12), 256, 0, stream>>>(
        x, Wq, bq, Wkv, bkv, qhi_g, qlo_g, khi_g, klo_g, v_ws);
    vsum_kernel<<<BATCH * HEADS, 256, 0, stream>>>(v_ws, vs_ws);
    attn_topk_kernel<<<dim3(SEQ / 64, BATCH * HEADS), 256, 0, stream>>>(
        qhi_g, qlo_g, khi_g, klo_g, v_ws, vs_ws, ao_ws);
    proj_gemm_kernel<<<dim3(MTOT / BM, CDIM / BN), 256, 0, stream>>>(
        ao_ws, Wp, bp, out);
}

// Round 4
// 559.606 us; speedup vs baseline: 1.8746x; 1.2075x over previous
//
#include <hip/hip_runtime.h>
#include <float.h>

#define BATCH 8
#define SEQ   1024
#define CDIM  512
#define HEADS 8
#define HD    64
#define TOPK  16
#define MTOT  (BATCH*SEQ)   // 8192

// ---------------- GEMM tile config ----------------
#define BM 128
#define BN 128
#define BKK 32

typedef short bf16x8 __attribute__((ext_vector_type(8)));
typedef float f32x4v __attribute__((ext_vector_type(4)));

// round-to-nearest bf16 split: f = hi + lo, each bf16; |err| ~ 2^-17 |f|
__device__ inline void bf16split(float f, unsigned short& h, unsigned short& l) {
    unsigned u = __float_as_uint(f);
    unsigned hr = (u + 0x7fffu + ((u >> 16) & 1u)) >> 16;
    h = (unsigned short)hr;
    float rest = f - __uint_as_float(hr << 16);
    unsigned v = __float_as_uint(rest);
    l = (unsigned short)((v + 0x7fffu + ((v >> 16) & 1u)) >> 16);
}

// ============================================================
// Kernel 1: fused QKV projection (fp32 core).
//   Epilogue: relu(q); split q,k into bf16 hi/lo planes; v stays fp32.
// ============================================================
__global__ __launch_bounds__(256) void qkv_gemm_kernel(
    const float* __restrict__ x,
    const float* __restrict__ Wq,  const float* __restrict__ bq,
    const float* __restrict__ Wkv, const float* __restrict__ bkv,
    unsigned short* __restrict__ qhi_g, unsigned short* __restrict__ qlo_g,
    unsigned short* __restrict__ khi_g, unsigned short* __restrict__ klo_g,
    float* __restrict__ v_ws)
{
    __shared__ float a_s[BKK][BM + 4];
    __shared__ float b_s[BKK][BN];

    const int bm = blockIdx.x;
    const int bn = blockIdx.y;           // 0..11 (0..3 q, 4..7 k, 8..11 v)
    const int tid = threadIdx.x;
    const int tx = tid & 15, ty = tid >> 4;
    const int row0 = bm * BM;

    const float* Bp; int ldb, bc0;
    if (bn < 4) { Bp = Wq;  ldb = CDIM;     bc0 = bn * BN; }
    else        { Bp = Wkv; ldb = 2 * CDIM; bc0 = bn * BN - CDIM; }

    float acc[8][8];
    #pragma unroll
    for (int i = 0; i < 8; i++)
        #pragma unroll
        for (int j = 0; j < 8; j++) acc[i][j] = 0.f;

    for (int kt = 0; kt < CDIM; kt += BKK) {
        #pragma unroll
        for (int i = 0; i < 4; i++) {
            int f = tid + i * 256;
            int r  = f >> 3, kq = f & 7;
            float4 av = *(const float4*)(x + (size_t)(row0 + r) * CDIM + kt + kq * 4);
            a_s[kq*4+0][r] = av.x; a_s[kq*4+1][r] = av.y;
            a_s[kq*4+2][r] = av.z; a_s[kq*4+3][r] = av.w;
        }
        #pragma unroll
        for (int i = 0; i < 4; i++) {
            int f = tid + i * 256;
            int kk = f >> 5, c4 = f & 31;
            *(float4*)&b_s[kk][c4*4] =
                *(const float4*)(Bp + (size_t)(kt + kk) * ldb + bc0 + c4 * 4);
        }
        __syncthreads();
        #pragma unroll
        for (int k = 0; k < BKK; k++) {
            float4 a0 = *(const float4*)&a_s[k][ty*4];
            float4 a1 = *(const float4*)&a_s[k][64 + ty*4];
            float4 b0 = *(const float4*)&b_s[k][tx*4];
            float4 b1 = *(const float4*)&b_s[k][64 + tx*4];
            float ar[8] = {a0.x,a0.y,a0.z,a0.w,a1.x,a1.y,a1.z,a1.w};
            float br[8] = {b0.x,b0.y,b0.z,b0.w,b1.x,b1.y,b1.z,b1.w};
            #pragma unroll
            for (int i = 0; i < 8; i++)
                #pragma unroll
                for (int j = 0; j < 8; j++)
                    acc[i][j] = fmaf(ar[i], br[j], acc[i][j]);
        }
        __syncthreads();
    }

    #pragma unroll
    for (int ih = 0; ih < 2; ih++) {
        #pragma unroll
        for (int i = 0; i < 4; i++) {
            int rg = row0 + ih*64 + ty*4 + i;
            int bb = rg >> 10, nn = rg & (SEQ - 1);
            #pragma unroll
            for (int jh = 0; jh < 2; jh++) {
                int cg = bn * BN + jh*64 + tx*4;
                float4 bias4 = (bn < 4) ? *(const float4*)(bq + cg)
                                        : *(const float4*)(bkv + cg - CDIM);
                float4 val;
                val.x = acc[ih*4+i][jh*4+0] + bias4.x;
                val.y = acc[ih*4+i][jh*4+1] + bias4.y;
                val.z = acc[ih*4+i][jh*4+2] + bias4.z;
                val.w = acc[ih*4+i][jh*4+3] + bias4.w;
                if (cg < CDIM) {
                    val.x = fmaxf(val.x, 0.f); val.y = fmaxf(val.y, 0.f);
                    val.z = fmaxf(val.z, 0.f); val.w = fmaxf(val.w, 0.f);
                    int h = cg >> 6, d = cg & 63;
                    size_t base = (((size_t)bb*HEADS + h)*SEQ + nn)*HD + d;
                    ushort4 hv, lv;
                    bf16split(val.x, hv.x, lv.x); bf16split(val.y, hv.y, lv.y);
                    bf16split(val.z, hv.z, lv.z); bf16split(val.w, hv.w, lv.w);
                    *(ushort4*)(qhi_g + base) = hv;
                    *(ushort4*)(qlo_g + base) = lv;
                } else {
                    int c2 = cg - CDIM;
                    int t = c2 >> 9, h = (c2 >> 6) & 7, d = c2 & 63;
                    size_t base = (((size_t)bb*HEADS + h)*SEQ + nn)*HD + d;
                    if (t == 0) {
                        ushort4 hv, lv;
                        bf16split(val.x, hv.x, lv.x); bf16split(val.y, hv.y, lv.y);
                        bf16split(val.z, hv.z, lv.z); bf16split(val.w, hv.w, lv.w);
                        *(ushort4*)(khi_g + base) = hv;
                        *(ushort4*)(klo_g + base) = lv;
                    } else {
                        *(float4*)(v_ws + base) = val;
                    }
                }
            }
        }
    }
}

// ============================================================
// Kernel 2: per-(b,h) column sum of V  -> vsum[bh][64]
// ============================================================
__global__ __launch_bounds__(256) void vsum_kernel(
    const float* __restrict__ v_ws, float* __restrict__ vsum_ws)
{
    __shared__ float red[4][HD];
    const int bh = blockIdx.x;
    const int d  = threadIdx.x & 63;
    const int sl = threadIdx.x >> 6;
    const float* vh = v_ws + (size_t)bh * SEQ * HD;
    float s = 0.f;
    for (int m = sl * 256; m < (sl + 1) * 256; m++) s += vh[(size_t)m * HD + d];
    red[sl][d] = s;
    __syncthreads();
    if (threadIdx.x < HD)
        vsum_ws[(size_t)bh * HD + d] = red[0][d] + red[1][d] + red[2][d] + red[3][d];
}

// ============================================================
// Kernel A: MFMA split-bf16 scores -> global fp32 [bhl][1024][1024]
// (scaled by D^-0.5). Double-buffered K tiles, no per-tile scan.
// LDS fragment order: chunk(ct, h, lane) holds
//   T[ct*16 + (lane&15)][h*32 + (lane>>4)*8 .. +8]
// ============================================================
__global__ __launch_bounds__(256) void score_kernel(
    const unsigned short* __restrict__ qhi_g, const unsigned short* __restrict__ qlo_g,
    const unsigned short* __restrict__ khi_g, const unsigned short* __restrict__ klo_g,
    float* __restrict__ s_g, int bh0)
{
    __shared__ __align__(16) short qhi_s[4096], qlo_s[4096];
    __shared__ __align__(16) short khi_s[2][4096], klo_s[2][4096];

    const int bhl = blockIdx.y;
    const int bh  = bh0 + bhl;
    const int n0  = blockIdx.x * 64;
    const int tid = threadIdx.x;
    const int lane = tid & 63, w = tid >> 6;
    const int r_st = tid >> 2, c4 = tid & 3;      // staging: row, 16-col segment
    const size_t hb = (size_t)bh * SEQ * HD;

    // staging chunk indices for (row r_st, 8-col segments s0, s0+1)
    const int s0 = c4 * 2, s1 = s0 + 1;
    const int cx0 = ((r_st >> 4)*2 + (s0 >> 2))*64 + (s0 & 3)*16 + (r_st & 15);
    const int cx1 = ((r_st >> 4)*2 + (s1 >> 2))*64 + (s1 & 3)*16 + (r_st & 15);

    // ---- stage Q tile (fragment order), hold fragments in registers ----
    {
        const unsigned short* qp  = qhi_g + hb + (size_t)(n0 + r_st)*HD + c4*16;
        const unsigned short* qp2 = qlo_g + hb + (size_t)(n0 + r_st)*HD + c4*16;
        uint4 h0 = *(const uint4*)qp,  h1 = *(const uint4*)(qp + 8);
        uint4 l0 = *(const uint4*)qp2, l1 = *(const uint4*)(qp2 + 8);
        *(uint4*)&qhi_s[cx0*8] = h0; *(uint4*)&qhi_s[cx1*8] = h1;
        *(uint4*)&qlo_s[cx0*8] = l0; *(uint4*)&qlo_s[cx1*8] = l1;
    }
    __syncthreads();
    bf16x8 qh[2], ql[2];
    #pragma unroll
    for (int h = 0; h < 2; h++) {
        qh[h] = *(bf16x8*)&qhi_s[((w*2 + h)*64 + lane)*8];
        ql[h] = *(bf16x8*)&qlo_s[((w*2 + h)*64 + lane)*8];
    }

    // ---- stage K tile 0 into buffer 0 ----
    {
        const unsigned short* kp  = khi_g + hb + (size_t)r_st*HD + c4*16;
        const unsigned short* kp2 = klo_g + hb + (size_t)r_st*HD + c4*16;
        uint4 kh0 = *(const uint4*)kp,  kh1 = *(const uint4*)(kp + 8);
        uint4 kl0 = *(const uint4*)kp2, kl1 = *(const uint4*)(kp2 + 8);
        *(uint4*)&khi_s[0][cx0*8] = kh0; *(uint4*)&khi_s[0][cx1*8] = kh1;
        *(uint4*)&klo_s[0][cx0*8] = kl0; *(uint4*)&klo_s[0][cx1*8] = kl1;
    }
    __syncthreads();

    float* srow_base = s_g + ((size_t)bhl << 20);

    for (int mt = 0; mt < SEQ / 64; mt++) {
        const int cur = mt & 1, nxt = cur ^ 1;
        // prefetch next K tile into registers
        uint4 kh0, kh1, kl0, kl1;
        if (mt + 1 < SEQ / 64) {
            const unsigned short* kp  = khi_g + hb + (size_t)((mt+1)*64 + r_st)*HD + c4*16;
            const unsigned short* kp2 = klo_g + hb + (size_t)((mt+1)*64 + r_st)*HD + c4*16;
            kh0 = *(const uint4*)kp;  kh1 = *(const uint4*)(kp + 8);
            kl0 = *(const uint4*)kp2; kl1 = *(const uint4*)(kp2 + 8);
        }

        // MFMA on current buffer + global stores
        #pragma unroll
        for (int ct = 0; ct < 4; ct++) {
            f32x4v acc = {0.f, 0.f, 0.f, 0.f};
            #pragma unroll
            for (int h = 0; h < 2; h++) {
                bf16x8 kfh = *(bf16x8*)&khi_s[cur][((ct*2 + h)*64 + lane)*8];
                bf16x8 kfl = *(bf16x8*)&klo_s[cur][((ct*2 + h)*64 + lane)*8];
                acc = __builtin_amdgcn_mfma_f32_16x16x32_bf16(qh[h], kfh, acc, 0, 0, 0);
                acc = __builtin_amdgcn_mfma_f32_16x16x32_bf16(qh[h], kfl, acc, 0, 0, 0);
                acc = __builtin_amdgcn_mfma_f32_16x16x32_bf16(ql[h], kfh, acc, 0, 0, 0);
            }
            // C/D: col = lane&15, row = (lane>>4)*4 + reg
            const int col  = mt*64 + ct*16 + (lane & 15);
            const int rowb = n0 + w*16 + (lane >> 4)*4;
            float* sp = srow_base + ((size_t)rowb << 10) + col;
            #pragma unroll
            for (int rg = 0; rg < 4; rg++)
                sp[(size_t)rg << 10] = acc[rg] * 0.125f;   // * D^-0.5
        }

        // write next K tile into the other buffer
        if (mt + 1 < SEQ / 64) {
            *(uint4*)&khi_s[nxt][cx0*8] = kh0; *(uint4*)&khi_s[nxt][cx1*8] = kh1;
            *(uint4*)&klo_s[nxt][cx0*8] = kl0; *(uint4*)&klo_s[nxt][cx1*8] = kl1;
        }
        __syncthreads();
    }
}

// ============================================================
// Kernel B: per-row top-16 (exact jax tie order) + sparse softmax + PV.
// One wave per (bh, n) row. Lane l holds score cols l*16..l*16+15 in
// registers; 16 rounds of wave argmax extraction (value desc, col asc).
// Zero LDS.
// ============================================================
__global__ __launch_bounds__(256) void topk_pv_kernel(
    const float* __restrict__ s_g, const float* __restrict__ v_ws,
    const float* __restrict__ vsum_ws, float* __restrict__ attn_out, int bh0)
{
    const int lane = threadIdx.x & 63;
    const int wid  = (blockIdx.x * 256 + threadIdx.x) >> 6;
    const int bhl  = wid >> 10;
    const int n    = wid & (SEQ - 1);
    const int bh   = bh0 + bhl;

    const float* srow = s_g + ((size_t)bhl << 20) + ((size_t)n << 10) + lane * 16;
    float v[16];
    #pragma unroll
    for (int i = 0; i < 4; i++) {
        float4 t = *(const float4*)(srow + i * 4);
        v[i*4+0] = t.x; v[i*4+1] = t.y; v[i*4+2] = t.z; v[i*4+3] = t.w;
    }

    float mv[TOPK]; int mi[TOPK];
    #pragma unroll
    for (int t = 0; t < TOPK; t++) {
        // local argmax (first max -> smallest col on ties)
        float bv = v[0]; int bj = 0;
        #pragma unroll
        for (int j = 1; j < 16; j++) { if (v[j] > bv) { bv = v[j]; bj = j; } }
        int bc = lane * 16 + bj;
        // wave argmax, tie -> smaller col (exact jax.lax.top_k order)
        #pragma unroll
        for (int off = 32; off; off >>= 1) {
            float ov = __shfl_xor(bv, off);
            int   oc = __shfl_xor(bc, off);
            if (ov > bv || (ov == bv && oc < bc)) { bv = ov; bc = oc; }
        }
        mv[t] = bv; mi[t] = bc;
        // owner lane removes the extracted element
        int jj = bc - lane * 16;            // in [0,16) only for owner
        #pragma unroll
        for (int j = 0; j < 16; j++) { if (j == jj) v[j] = -FLT_MAX; }
    }

    // sparse softmax over full row: non-topk entries contribute exp(0)=1
    float mx = fmaxf(mv[0], 0.f);           // mv[0] is the row max
    float e  = expf(-mx);
    float Z  = (float)(SEQ - TOPK) * e;
    float wexp[TOPK];
    #pragma unroll
    for (int t = 0; t < TOPK; t++) { wexp[t] = expf(mv[t] - mx); Z += wexp[t]; }
    float invZ = 1.f / Z;
    float ez = e * invZ;

    // PV: lane = output dim d
    const float* vh = v_ws + ((size_t)bh << 16);
    float acc = ez * vsum_ws[(bh << 6) + lane];
    #pragma unroll
    for (int t = 0; t < TOPK; t++)
        acc = fmaf((wexp[t] - e) * invZ, vh[((size_t)mi[t] << 6) + lane], acc);

    const int b = bh >> 3, h = bh & 7;
    attn_out[(((size_t)b << 10) + n) * CDIM + (h << 6) + lane] = acc;
}

// ============================================================
// Kernel 4: output projection  out = attn_out @ Wp + bp
// ============================================================
__global__ __launch_bounds__(256) void proj_gemm_kernel(
    const float* __restrict__ A,
    const float* __restrict__ Wp, const float* __restrict__ bp,
    float* __restrict__ out)
{
    __shared__ float a_s[BKK][BM + 4];
    __shared__ float b_s[BKK][BN];

    const int bm = blockIdx.x;
    const int bn = blockIdx.y;
    const int tid = threadIdx.x;
    const int tx = tid & 15, ty = tid >> 4;
    const int row0 = bm * BM;
    const int bc0 = bn * BN;

    float acc[8][8];
    #pragma unroll
    for (int i = 0; i < 8; i++)
        #pragma unroll
        for (int j = 0; j < 8; j++) acc[i][j] = 0.f;

    for (int kt = 0; kt < CDIM; kt += BKK) {
        #pragma unroll
        for (int i = 0; i < 4; i++) {
            int f = tid + i * 256;
            int r = f >> 3, kq = f & 7;
            float4 av = *(const float4*)(A + (size_t)(row0 + r) * CDIM + kt + kq * 4);
            a_s[kq*4+0][r] = av.x; a_s[kq*4+1][r] = av.y;
            a_s[kq*4+2][r] = av.z; a_s[kq*4+3][r] = av.w;
        }
        #pragma unroll
        for (int i = 0; i < 4; i++) {
            int f = tid + i * 256;
            int kk = f >> 5, c4 = f & 31;
            *(float4*)&b_s[kk][c4*4] =
                *(const float4*)(Wp + (size_t)(kt + kk) * CDIM + bc0 + c4 * 4);
        }
        __syncthreads();
        #pragma unroll
        for (int k = 0; k < BKK; k++) {
            float4 a0 = *(const float4*)&a_s[k][ty*4];
            float4 a1 = *(const float4*)&a_s[k][64 + ty*4];
            float4 b0 = *(const float4*)&b_s[k][tx*4];
            float4 b1 = *(const float4*)&b_s[k][64 + tx*4];
            float ar[8] = {a0.x,a0.y,a0.z,a0.w,a1.x,a1.y,a1.z,a1.w};
            float br[8] = {b0.x,b0.y,b0.z,b0.w,b1.x,b1.y,b1.z,b1.w};
            #pragma unroll
            for (int i = 0; i < 8; i++)
                #pragma unroll
                for (int j = 0; j < 8; j++)
                    acc[i][j] = fmaf(ar[i], br[j], acc[i][j]);
        }
        __syncthreads();
    }

    #pragma unroll
    for (int ih = 0; ih < 2; ih++) {
        #pragma unroll
        for (int i = 0; i < 4; i++) {
            int rg = row0 + ih*64 + ty*4 + i;
            #pragma unroll
            for (int jh = 0; jh < 2; jh++) {
                int cg = bc0 + jh*64 + tx*4;
                float4 bias4 = *(const float4*)(bp + cg);
                float4 val;
                val.x = acc[ih*4+i][jh*4+0] + bias4.x;
                val.y = acc[ih*4+i][jh*4+1] + bias4.y;
                val.z = acc[ih*4+i][jh*4+2] + bias4.z;
                val.w = acc[ih*4+i][jh*4+3] + bias4.w;
                *(float4*)(out + (size_t)rg * CDIM + cg) = val;
            }
        }
    }
}

// ============================================================
extern "C" void kernel_launch(void* const* d_in, const int* in_sizes, int n_in,
                              void* d_out, int out_size, void* d_ws, size_t ws_size,
                              hipStream_t stream)
{
    const float* x   = (const float*)d_in[0];
    const float* Wq  = (const float*)d_in[1];
    const float* bq  = (const float*)d_in[2];
    const float* Wkv = (const float*)d_in[3];
    const float* bkv = (const float*)d_in[4];
    const float* Wp  = (const float*)d_in[5];
    const float* bp  = (const float*)d_in[6];
    float* out = (float*)d_out;

    // workspace (floats):
    //   v (HSZ) | ao (HSZ) | vsum (4096) | 4 ushort planes (2*HSZ fl) | scores
    const size_t HSZ = (size_t)BATCH * HEADS * SEQ * HD;   // 4,194,304
    float* ws    = (float*)d_ws;
    float* v_ws  = ws;
    float* ao_ws = ws + HSZ;
    float* vs_ws = ws + 2 * HSZ;
    unsigned short* qhi_g = (unsigned short*)(ws + 2 * HSZ + 4096);
    unsigned short* qlo_g = qhi_g + HSZ;
    unsigned short* khi_g = qhi_g + 2 * HSZ;
    unsigned short* klo_g = qhi_g + 3 * HSZ;
    float* s_g = ws + 4 * HSZ + 4096;

    // chunk bh groups so the fp32 score buffer fits in remaining scratch
    const size_t base_fl  = 4 * HSZ + 4096;
    const size_t avail_fl = (ws_size / 4 > base_fl) ? (ws_size / 4 - base_fl) : 0;
    int G = 64;
    while (G > 1 && (size_t)G * SEQ * SEQ > avail_fl) G >>= 1;

    qkv_gemm_kernel<<<dim3(MTOT / BM, 12), 256, 0, stream>>>(
        x, Wq, bq, Wkv, bkv, qhi_g, qlo_g, khi_g, klo_g, v_ws);
    vsum_kernel<<<BATCH * HEADS, 256, 0, stream>>>(v_ws, vs_ws);
    for (int bh0 = 0; bh0 < BATCH * HEADS; bh0 += G) {
        score_kernel<<<dim3(SEQ / 64, G), 256, 0, stream>>>(
            qhi_g, qlo_g, khi_g, klo_g, s_g, bh0);
        topk_pv_kernel<<<dim3(G * (SEQ / 4)), 256, 0, stream>>>(
            s_g, v_ws, vs_ws, ao_ws, bh0);
    }
    proj_gemm_kernel<<<dim3(MTOT / BM, CDIM / BN), 256, 0, stream>>>(
        ao_ws, Wp, bp, out);
}